// Round 13
// baseline (72.788 us; speedup 1.0000x reference)
//
#include <hip/hip_runtime.h>
#include <math.h>

// Problem constants
#define BATCH 2
#define SEQ   2048
#define DIM   1024
#define RANK  256
#define HEADS 16
#define HS    16
#define DH    64
#define MROWS 4096

#define QSCALE 0.36067376f   // 0.25 * log2(e), folded into normalized q

typedef __attribute__((ext_vector_type(8)))  short    short8;   // 8 bf16
typedef __attribute__((ext_vector_type(4)))  float    f32x4;
typedef __attribute__((ext_vector_type(16))) float    f32x16;
typedef __attribute__((ext_vector_type(2)))  unsigned uint2v;

#define GPTR const __attribute__((address_space(1))) unsigned int*
#define LPTR __attribute__((address_space(3))) unsigned int*

__device__ __forceinline__ unsigned short f2bf(float f) {
    union { float f; unsigned u; } v; v.f = f;
    return (unsigned short)((v.u + 0x7FFFu + ((v.u >> 16) & 1u)) >> 16);  // RNE
}
__device__ __forceinline__ float bf2f(unsigned short h) {
    union { unsigned u; float f; } v; v.u = ((unsigned)h) << 16;
    return v.f;
}

// ---------------- fused f32 -> bf16 convert for x, Wqk, Wv ----------------
#define XQ   1048576
#define WQKQ 131072
#define WVQ  262144
__global__ __launch_bounds__(256) void conv3(const float* __restrict__ x,
                                             const float* __restrict__ wqk,
                                             const float* __restrict__ wv,
                                             unsigned short* __restrict__ xb,
                                             unsigned short* __restrict__ wcat)
{
    const int i = blockIdx.x * 256 + threadIdx.x;
    const float* src; unsigned short* dst; int j;
    if (i < XQ)              { src = x;   dst = xb;   j = i; }
    else if (i < XQ + WQKQ)  { src = wqk; dst = wcat; j = i - XQ; }
    else                     { src = wv;  dst = wcat + (size_t)4 * WQKQ; j = i - XQ - WQKQ; }
    float4 v = ((const float4*)src)[j];
    ushort4 o; o.x = f2bf(v.x); o.y = f2bf(v.y); o.z = f2bf(v.z); o.w = f2bf(v.w);
    ((ushort4*)dst)[j] = o;
}

// ---------------- MFMA GEMM: 128x64 tile, BK=64, DBUF LDS + counted vmcnt ----------------
// V output written in MFMA-FRAGMENT order (vt2): [bh][k>>6][g][half][l31][hi][e]
// so attention V loads are lane-linear 1KB transactions.
__global__ __launch_bounds__(256, 3) void gemm_mfma(const unsigned short* __restrict__ A,
                                                    const unsigned short* __restrict__ W,
                                                    unsigned short* __restrict__ qkb,
                                                    unsigned short* __restrict__ vt2)
{
    __shared__ __align__(16) unsigned short Alds[2][128 * 64];  // 32 KB
    __shared__ __align__(16) unsigned short Blds[2][64 * 64];   // 16 KB

    const int tid = threadIdx.x;
    const int w = tid >> 6, lane = tid & 63;
    const int lr = lane & 15, lg = lane >> 4;
    const int wm = w >> 1, wn = w & 1;

    const int Lf = blockIdx.x;                 // 768 blocks
    const int wg = (Lf & 7) * 96 + (Lf >> 3);  // bijective XCD chunking
    const int bm = (wg & 31) * 128;
    const int bn = (wg >> 5) * 64;

    const int rs = lane >> 3, cs = lane & 7;

    f32x4 acc[4][2] = {};

#define STAGEG(kt_, buf_) do {                                                        \
        const int k0_ = (kt_) * 64;                                                   \
        _Pragma("unroll")                                                             \
        for (int i = 0; i < 4; ++i) {                                                 \
            const int r = w * 32 + i * 8 + rs;                                        \
            __builtin_amdgcn_global_load_lds(                                         \
                (GPTR)&A[(size_t)(bm + r) * 1024 + k0_ + 8 * (cs ^ (r & 7))],         \
                (LPTR)&Alds[buf_][(w * 32 + i * 8) * 64], 16, 0, 0);                  \
        }                                                                             \
        _Pragma("unroll")                                                             \
        for (int i = 0; i < 2; ++i) {                                                 \
            const int r = w * 16 + i * 8 + rs;                                        \
            __builtin_amdgcn_global_load_lds(                                         \
                (GPTR)&W[(size_t)(bn + r) * 1024 + k0_ + 8 * (cs ^ (r & 7))],         \
                (LPTR)&Blds[buf_][(w * 16 + i * 8) * 64], 16, 0, 0);                  \
        }                                                                             \
    } while (0)

    STAGEG(0, 0);

    #pragma unroll 1
    for (int kt = 0; kt < 16; ++kt) {
        if (kt + 1 < 16) {
            STAGEG(kt + 1, (kt + 1) & 1);
            asm volatile("s_waitcnt vmcnt(6)" ::: "memory");   // drain tile kt only
        } else {
            asm volatile("s_waitcnt vmcnt(0)" ::: "memory");
        }
        __builtin_amdgcn_sched_barrier(0);
        __builtin_amdgcn_s_barrier();

        const int buf = kt & 1;
        #pragma unroll
        for (int kk = 0; kk < 2; ++kk) {
            short8 af[4], bfr[2];
            #pragma unroll
            for (int mi = 0; mi < 4; ++mi) {
                const int row = wm * 64 + mi * 16 + lr;
                af[mi] = *(const short8*)&Alds[buf][row * 64 + 8 * ((kk * 4 + lg) ^ (row & 7))];
            }
            #pragma unroll
            for (int ni = 0; ni < 2; ++ni) {
                const int row = wn * 32 + ni * 16 + lr;
                bfr[ni] = *(const short8*)&Blds[buf][row * 64 + 8 * ((kk * 4 + lg) ^ (row & 7))];
            }
            #pragma unroll
            for (int mi = 0; mi < 4; ++mi)
                #pragma unroll
                for (int ni = 0; ni < 2; ++ni)
                    acc[mi][ni] = __builtin_amdgcn_mfma_f32_16x16x32_bf16(af[mi], bfr[ni], acc[mi][ni], 0, 0, 0);
        }
        __builtin_amdgcn_s_barrier();   // all waves done with buf before restage
    }
#undef STAGEG

    if (bn < 512) {
        #pragma unroll
        for (int mi = 0; mi < 4; ++mi) {
            const int rbase = bm + wm * 64 + mi * 16 + lg * 4;
            #pragma unroll
            for (int ni = 0; ni < 2; ++ni) {
                const int col = bn + wn * 32 + ni * 16 + lr;
                #pragma unroll
                for (int r = 0; r < 4; ++r)
                    qkb[(size_t)(rbase + r) * 512 + col] = f2bf(acc[mi][ni][r]);
            }
        }
    } else {
        const int nb = bn - 512;
        #pragma unroll
        for (int mi = 0; mi < 4; ++mi) {
            const int m = bm + wm * 64 + mi * 16 + lg * 4;   // global row -> key
            const int bb = m >> 11, k = m & 2047;            // k is 4-aligned
            #pragma unroll
            for (int ni = 0; ni < 2; ++ni) {
                const int d = nb + wn * 32 + ni * 16 + lr;   // 0..1023
                const int h = d >> 6, dh = d & 63;
                ushort4 pk;
                pk.x = f2bf(acc[mi][ni][0]); pk.y = f2bf(acc[mi][ni][1]);
                pk.z = f2bf(acc[mi][ni][2]); pk.w = f2bf(acc[mi][ni][3]);
                const size_t off = (size_t)(bb * HEADS + h) * (SEQ * 64)
                                 + (k >> 6) * 4096 + ((k >> 4) & 3) * 1024
                                 + (dh >> 5) * 512 + (dh & 31) * 16
                                 + ((k >> 3) & 1) * 8 + (k & 7);
                *(ushort4*)&vt2[off] = pk;
            }
        }
    }
}

// ---------------- L2 normalize; outputs HEAD-MAJOR qn/kn [bh][n][16] ----------------
__global__ __launch_bounds__(256) void l2norm_split(const unsigned short* __restrict__ qkb,
                                                    unsigned short* __restrict__ qn,
                                                    unsigned short* __restrict__ kn)
{
    const int row = blockIdx.x;
    const int t = threadIdx.x;
    const unsigned short* p = qkb + (size_t)row * 512;
    float q = bf2f(p[t]);
    float k = bf2f(p[t + 256]);
    float sq = q * q, sk = k * k;
    #pragma unroll
    for (int off = 32; off > 0; off >>= 1) {
        sq += __shfl_down(sq, off);
        sk += __shfl_down(sk, off);
    }
    __shared__ float sh[8];
    const int wid = t >> 6;
    if ((t & 63) == 0) { sh[wid * 2] = sq; sh[wid * 2 + 1] = sk; }
    __syncthreads();
    sq = sh[0] + sh[2] + sh[4] + sh[6];
    sk = sh[1] + sh[3] + sh[5] + sh[7];
    const float rq = QSCALE / fmaxf(sqrtf(sq), 1e-6f);
    const float rk = 1.0f   / fmaxf(sqrtf(sk), 1e-6f);

    const int b = row >> 11, n = row & 2047;
    const int head = t >> 4, hs = t & 15;
    const size_t o = (((size_t)b * HEADS + head) * SEQ + n) * 16 + hs;
    qn[o] = f2bf(q * rq);
    kn[o] = f2bf(k * rk);
}

// ---------------- attn: BARRIER-FREE, zero-LDS, fragment-exact V loads ----------------
// Each wave owns ONE 32-row q-band and its full causal prefix (64-key tiles):
// K/Q coalesced from head-major buffers, V via vt2 (lane-linear 1KB loads),
// everything L2-resident via XCD pinning (L&31=bh). No __syncthreads anywhere.
// Block = 4 bands {j, 63-j, 31-j, 32+j} -> uniform 66 tiles per block.

template<bool MASK>
__device__ __forceinline__ void tile_nb(const short8 ak0, const short8 ak1, const short8 bq,
                                        const short8 vb[4][2], int hi, f32x16 o[2], float& lp)
{
    const f32x16 z = {};
    short8 pa[4];

    const f32x16 s0 = __builtin_amdgcn_mfma_f32_32x32x16_bf16(ak0, bq, z, 0, 0, 0);
    {
        float p0[16];
        #pragma unroll
        for (int r = 0; r < 16; ++r) {
            float e = __builtin_exp2f(s0[r]);
            if (MASK) {
                const int kl = (r & 3) + 8 * (r >> 2) + 4 * hi;   // key - kb
                e = (kl > 0) ? 0.0f : e;   // placeholder; real check below via qrel
            }
            p0[r] = e;
        }
        // (masked variant recomputed with qrel in caller-specialized code below)
        #pragma unroll
        for (int r = 0; r < 16; ++r) lp += p0[r];
        #pragma unroll
        for (int g = 0; g < 2; ++g) {
            const int jj = 2 * g;
            unsigned a0, a1, b0, b1;
            asm("v_cvt_pk_bf16_f32 %0, %1, %2" : "=v"(a0) : "v"(p0[4*jj]),     "v"(p0[4*jj + 1]));
            asm("v_cvt_pk_bf16_f32 %0, %1, %2" : "=v"(b0) : "v"(p0[4*jj + 2]), "v"(p0[4*jj + 3]));
            asm("v_cvt_pk_bf16_f32 %0, %1, %2" : "=v"(a1) : "v"(p0[4*jj + 4]), "v"(p0[4*jj + 5]));
            asm("v_cvt_pk_bf16_f32 %0, %1, %2" : "=v"(b1) : "v"(p0[4*jj + 6]), "v"(p0[4*jj + 7]));
            const uint2v r0 = __builtin_amdgcn_permlane32_swap(a0, a1, false, false);
            const uint2v r1 = __builtin_amdgcn_permlane32_swap(b0, b1, false, false);
            union { short8 s; unsigned u[4]; } pu;
            pu.u[0] = r0[0]; pu.u[1] = r1[0]; pu.u[2] = r0[1]; pu.u[3] = r1[1];
            pa[g] = pu.s;
        }
    }
    const f32x16 s1 = __builtin_amdgcn_mfma_f32_32x32x16_bf16(ak1, bq, z, 0, 0, 0);
    {
        float p1[16];
        #pragma unroll
        for (int r = 0; r < 16; ++r) {
            const float e = __builtin_exp2f(s1[r]);
            p1[r] = e; lp += e;
        }
        #pragma unroll
        for (int g = 0; g < 2; ++g) {
            const int jj = 2 * g;
            unsigned a0, a1, b0, b1;
            asm("v_cvt_pk_bf16_f32 %0, %1, %2" : "=v"(a0) : "v"(p1[4*jj]),     "v"(p1[4*jj + 1]));
            asm("v_cvt_pk_bf16_f32 %0, %1, %2" : "=v"(b0) : "v"(p1[4*jj + 2]), "v"(p1[4*jj + 3]));
            asm("v_cvt_pk_bf16_f32 %0, %1, %2" : "=v"(a1) : "v"(p1[4*jj + 4]), "v"(p1[4*jj + 5]));
            asm("v_cvt_pk_bf16_f32 %0, %1, %2" : "=v"(b1) : "v"(p1[4*jj + 6]), "v"(p1[4*jj + 7]));
            const uint2v r0 = __builtin_amdgcn_permlane32_swap(a0, a1, false, false);
            const uint2v r1 = __builtin_amdgcn_permlane32_swap(b0, b1, false, false);
            union { short8 s; unsigned u[4]; } pu;
            pu.u[0] = r0[0]; pu.u[1] = r1[0]; pu.u[2] = r0[1]; pu.u[3] = r1[1];
            pa[2 + g] = pu.s;
        }
    }

    #pragma unroll
    for (int g = 0; g < 4; ++g)
        #pragma unroll
        for (int half = 0; half < 2; ++half)
            o[half] = __builtin_amdgcn_mfma_f32_32x32x16_bf16(pa[g], vb[g][half], o[half], 0, 0, 0);
}

// masked last tile: needs kb and qg
__device__ __forceinline__ void tile_nb_mask(const short8 ak0, const short8 ak1, const short8 bq,
                                             const short8 vb[4][2], int kb, int hi, int qg,
                                             f32x16 o[2], float& lp)
{
    const f32x16 z = {};
    short8 pa[4];
    const f32x16 s0 = __builtin_amdgcn_mfma_f32_32x32x16_bf16(ak0, bq, z, 0, 0, 0);
    const f32x16 s1 = __builtin_amdgcn_mfma_f32_32x32x16_bf16(ak1, bq, z, 0, 0, 0);
    float p0[16], p1[16];
    #pragma unroll
    for (int r = 0; r < 16; ++r) {
        const int kl = kb + (r & 3) + 8 * (r >> 2) + 4 * hi;
        float e0 = __builtin_exp2f(s0[r]);
        float e1 = __builtin_exp2f(s1[r]);
        e0 = (kl > qg) ? 0.0f : e0;
        e1 = (kl + 32 > qg) ? 0.0f : e1;
        p0[r] = e0; p1[r] = e1;
        lp += e0 + e1;
    }
    #pragma unroll
    for (int g = 0; g < 4; ++g) {
        const float* pc = (g < 2) ? p0 : p1;
        const int jj = 2 * (g & 1);
        unsigned a0, a1, b0, b1;
        asm("v_cvt_pk_bf16_f32 %0, %1, %2" : "=v"(a0) : "v"(pc[4*jj]),     "v"(pc[4*jj + 1]));
        asm("v_cvt_pk_bf16_f32 %0, %1, %2" : "=v"(b0) : "v"(pc[4*jj + 2]), "v"(pc[4*jj + 3]));
        asm("v_cvt_pk_bf16_f32 %0, %1, %2" : "=v"(a1) : "v"(pc[4*jj + 4]), "v"(pc[4*jj + 5]));
        asm("v_cvt_pk_bf16_f32 %0, %1, %2" : "=v"(b1) : "v"(pc[4*jj + 6]), "v"(pc[4*jj + 7]));
        const uint2v r0 = __builtin_amdgcn_permlane32_swap(a0, a1, false, false);
        const uint2v r1 = __builtin_amdgcn_permlane32_swap(b0, b1, false, false);
        union { short8 s; unsigned u[4]; } pu;
        pu.u[0] = r0[0]; pu.u[1] = r1[0]; pu.u[2] = r0[1]; pu.u[3] = r1[1];
        pa[g] = pu.s;
    }
    #pragma unroll
    for (int g = 0; g < 4; ++g)
        #pragma unroll
        for (int half = 0; half < 2; ++half)
            o[half] = __builtin_amdgcn_mfma_f32_32x32x16_bf16(pa[g], vb[g][half], o[half], 0, 0, 0);
}

__global__ __launch_bounds__(256, 2) void attn_nb(const unsigned short* __restrict__ qn,
                                                  const unsigned short* __restrict__ kn,
                                                  const unsigned short* __restrict__ vt2,
                                                  float* __restrict__ out)
{
    const int L = blockIdx.x;            // 512; L%8 == bh%8 -> XCD-pinned
    const int bh = L & 31;
    const int j  = L >> 5;               // 0..15
    const int h = bh & 15, b = bh >> 4;

    const int tid = threadIdx.x, w = tid >> 6, lane = tid & 63;
    const int l31 = lane & 31, hi = lane >> 5;

    // bands {j, 63-j, 31-j, 32+j}: uniform 66 tiles per block
    const int band = (w == 0) ? j : (w == 1) ? 63 - j : (w == 2) ? 31 - j : 32 + j;
    const int nts = (band >> 1) + 1;     // 64-key tiles in causal prefix
    const int qg = band * 32 + l31;

    const unsigned short* qbh = qn + (size_t)bh * SEQ * 16;
    const unsigned short* kbh = kn + (size_t)bh * SEQ * 16;
    const unsigned short* vbh = vt2 + (size_t)bh * (SEQ * 64);

    const short8 bq = *(const short8*)&qbh[(size_t)qg * 16 + 8 * hi];

    f32x16 o[2] = {};
    float lp = 0.0f;

    const unsigned short* kwin = kbh + l31 * 16 + 8 * hi;       // + t*1024
    const unsigned short* vwin = vbh + l31 * 16 + hi * 8;       // + t*4096 + g*1024 + half*512

    short8 ak0 = *(const short8*)(kwin);
    short8 ak1 = *(const short8*)(kwin + 32 * 16);

    #pragma unroll 1
    for (int t = 0; t < nts; ++t) {
        // V for THIS tile: 8 lane-linear 1KB loads; consumed only after QK+exp
        short8 vb[4][2];
        #pragma unroll
        for (int g = 0; g < 4; ++g)
            #pragma unroll
            for (int half = 0; half < 2; ++half)
                vb[g][half] = *(const short8*)(vwin + (size_t)t * 4096 + g * 1024 + half * 512);

        // K prefetch for next tile
        short8 an0 = ak0, an1 = ak1;
        if (t + 1 < nts) {
            an0 = *(const short8*)(kwin + (size_t)(t + 1) * 1024);
            an1 = *(const short8*)(kwin + (size_t)(t + 1) * 1024 + 32 * 16);
        }

        if (t < nts - 1)
            tile_nb<false>(ak0, ak1, bq, vb, hi, o, lp);
        else
            tile_nb_mask(ak0, ak1, bq, vb, t * 64, hi, qg, o, lp);

        ak0 = an0; ak1 = an1;
    }

    // ---- epilogue: in-wave only ----
    lp += __shfl_xor(lp, 32);            // fold hi halves -> per-q totals (q = l31)
    const float inv = 1.0f / fmaxf(lp, 1e-6f);

    #pragma unroll
    for (int r = 0; r < 16; ++r) {
        const int q = (r & 3) + 8 * (r >> 2) + 4 * hi;
        const float iv = __shfl(inv, q);
        #pragma unroll
        for (int half = 0; half < 2; ++half) {
            const float v = o[half][r] * iv;
            __builtin_nontemporal_store(v,
                &out[((size_t)b * SEQ + band * 32 + q) * DIM + h * DH + half * 32 + l31]);
        }
    }
}

extern "C" void kernel_launch(void* const* d_in, const int* in_sizes, int n_in,
                              void* d_out, int out_size, void* d_ws, size_t ws_size,
                              hipStream_t stream)
{
    const float* x   = (const float*)d_in[0];
    // d_in[1] = mask (causal, analytic)
    const float* Wqk = (const float*)d_in[2];
    const float* Wv  = (const float*)d_in[3];
    float* out = (float*)d_out;

    // workspace: xb 8MB | qkb 4MB | vt2 8MB | wcat 3MB ; qn/kn (head-major) overlay xb
    unsigned short* xb   = (unsigned short*)d_ws;
    unsigned short* qkb  = xb  + (size_t)MROWS * DIM;
    unsigned short* vt2  = qkb + (size_t)MROWS * 512;
    unsigned short* wcat = vt2 + (size_t)BATCH * DIM * SEQ;
    unsigned short* qn = xb;                               // [32 bh][2048][16]
    unsigned short* kn = xb + (size_t)32 * SEQ * 16;

    conv3<<<5632, 256, 0, stream>>>(x, Wqk, Wv, xb, wcat);
    gemm_mfma<<<768, 256, 0, stream>>>(xb, wcat, qkb, vt2);
    l2norm_split<<<MROWS, 256, 0, stream>>>(qkb, qn, kn);
    attn_nb<<<512, 256, 0, stream>>>(qn, kn, vt2, out);
}